// Round 1
// baseline (211.938 us; speedup 1.0000x reference)
//
#include <hip/hip_runtime.h>
#include <math.h>

namespace {
constexpr int Bc = 4, Sc = 4096, Dc = 768, Gc = 64, Wc = 16, Rc = 4;
constexpr int NWc = Sc / Wc;          // 256 windows per batch row
constexpr int KEEPc = Wc - Rc;        // 12 kept tokens per window
constexpr int Ec = Wc - 1;            // 15 adjacent edges
constexpr int NQc = Dc / 4;           // 192 float4 per x row
constexpr size_t X_ELEMS = (size_t)Bc * NWc * KEEPc * Dc;  // 9437184
constexpr size_t S_ELEMS = (size_t)Bc * NWc * KEEPc * Sc;  // 50331648
}

// One block per window. 4 waves split the K=768 dot; lane = G-column.
__global__ __launch_bounds__(256, 4)
void tm_select_x(const float* __restrict__ x, const int* __restrict__ pos,
                 const float* __restrict__ Wg, float* __restrict__ out,
                 int* __restrict__ meta) {
  const int wid = blockIdx.x;          // 0..1023
  const int b = wid >> 8;
  const int n = wid & (NWc - 1);
  const int tid = threadIdx.x;
  const int lane = tid & 63;
  const int wq = tid >> 6;

  const float* xr = x + (size_t)(b * Sc + n * Wc) * Dc;
  const float4* xr4 = reinterpret_cast<const float4*>(xr);

  // ---- g = xw @ Wg, each wave does a 192-wide d-slice for all 16 tokens ----
  float acc[Wc];
#pragma unroll
  for (int w = 0; w < Wc; ++w) acc[w] = 0.f;

  const int q0 = wq * (NQc / 4);       // 48 float4-steps per wave
  for (int q = 0; q < NQc / 4; ++q) {
    const int d4 = q0 + q;
    const int d = d4 * 4;
    const float w0 = Wg[(size_t)d * Gc + lane];          // coalesced 256B
    const float w1 = Wg[(size_t)(d + 1) * Gc + lane];
    const float w2 = Wg[(size_t)(d + 2) * Gc + lane];
    const float w3 = Wg[(size_t)(d + 3) * Gc + lane];
#pragma unroll
    for (int w = 0; w < Wc; ++w) {
      const float4 xv = xr4[w * NQc + d4];               // wave-broadcast 16B
      acc[w] = fmaf(xv.x, w0, acc[w]);
      acc[w] = fmaf(xv.y, w1, acc[w]);
      acc[w] = fmaf(xv.z, w2, acc[w]);
      acc[w] = fmaf(xv.w, w3, acc[w]);
    }
  }

  __shared__ float part[4][Wc][64];    // 16 KiB
#pragma unroll
  for (int w = 0; w < Wc; ++w) part[wq][w][lane] = acc[w];
  __syncthreads();

  // ---- norms^2 (16) and adjacent dots (15) via butterfly; all lanes end equal
  float red[Wc + Ec];
  {
    float g[Wc];
#pragma unroll
    for (int w = 0; w < Wc; ++w)
      g[w] = part[0][w][lane] + part[1][w][lane] + part[2][w][lane] + part[3][w][lane];
#pragma unroll
    for (int w = 0; w < Wc; ++w) red[w] = g[w] * g[w];
#pragma unroll
    for (int e = 0; e < Ec; ++e) red[Wc + e] = g[e] * g[e + 1];
  }
#pragma unroll
  for (int m = 1; m < 64; m <<= 1) {
#pragma unroll
    for (int i = 0; i < Wc + Ec; ++i) red[i] += __shfl_xor(red[i], m, 64);
  }

  float nr[Wc];
#pragma unroll
  for (int w = 0; w < Wc; ++w) nr[w] = sqrtf(red[w]);

  float sv[Ec];
#pragma unroll
  for (int e = 0; e < Ec; ++e)
    sv[e] = red[Wc + e] / (fmaxf(nr[e], 1e-12f) * fmaxf(nr[e + 1], 1e-12f));

  // ---- greedy matching: 4 rounds of max-compatible-edge (== stable-sorted greedy)
  unsigned sel = 0, used = 0;
#pragma unroll
  for (int round = 0; round < Rc; ++round) {
    float best = -1e30f;
    int bi = 0;
#pragma unroll
    for (int e = 0; e < Ec; ++e) {
      const bool ok = ((used >> e) & 3u) == 0u;
      const float v = ok ? sv[e] : -1e30f;
      if (v > best) { best = v; bi = e; }   // strict > => smallest index on ties
    }
    sel |= (1u << bi);
    used |= (3u << bi);
  }

  // ---- x_out: 3 kept rows per wave ----
#pragma unroll
  for (int j = 0; j < 3; ++j) {
    const int k = wq * 3 + j;
    int w = 0, c = 0;
#pragma unroll
    for (int t = 0; t < Wc; ++t) {
      const bool kept = (t == 0) || (((sel >> (t - 1)) & 1u) == 0u);
      if (kept && c == k) w = t;
      c += kept ? 1 : 0;
    }
    const bool mg = (w < Ec) && (((sel >> w) & 1u) != 0u);
    float wi = 0.f, wj = 0.f;                 // dynamic index via select chain
#pragma unroll
    for (int t = 0; t < Wc; ++t) {
      wi = (t == w) ? nr[t] : wi;
      wj = (t == (w + 1)) ? nr[t] : wj;
    }
    float aS = 1.f, bS = 0.f;
    if (mg) {
      const float tot = wi + wj + 1e-8f;
      aS = wi / tot;
      bS = wj / tot;
    }
    const float4* r1 = xr4 + (size_t)w * NQc;
    const float4* r2 = xr4 + (size_t)(mg ? (w + 1) : w) * NQc;
    float4* o = reinterpret_cast<float4*>(out + (size_t)((b * NWc + n) * KEEPc + k) * Dc);
#pragma unroll
    for (int it = 0; it < 3; ++it) {
      const int i = lane + 64 * it;
      const float4 a = r1[i];
      const float4 bb = r2[i];
      float4 rr;
      rr.x = fmaf(aS, a.x, bS * bb.x);
      rr.y = fmaf(aS, a.y, bS * bb.y);
      rr.z = fmaf(aS, a.z, bS * bb.z);
      rr.w = fmaf(aS, a.w, bS * bb.w);
      o[i] = rr;
    }
  }

  // ---- meta for s-kernel + p_out (as float; whole d_out is f32) ----
  if (wq == 0 && lane < KEEPc) {
    const int k = lane;
    int w = 0, c = 0;
#pragma unroll
    for (int t = 0; t < Wc; ++t) {
      const bool kept = (t == 0) || (((sel >> (t - 1)) & 1u) == 0u);
      if (kept && c == k) w = t;
      c += kept ? 1 : 0;
    }
    const bool mg = (w < Ec) && (((sel >> w) & 1u) != 0u);
    meta[wid * KEEPc + k] = w | (mg ? 16 : 0);
    const int p = pos[b * Sc + n * Wc + w];
    out[X_ELEMS + S_ELEMS + (size_t)((b * NWc + n) * KEEPc + k)] = (float)p;
  }
}

// One block per s_out row: stream-copy or stream-add two adjacent 16 KB rows.
__global__ __launch_bounds__(256)
void tm_merge_s(const float* __restrict__ src, const int* __restrict__ meta,
                float* __restrict__ outs) {
  const int gid = blockIdx.x;              // 0..12287 == (b*NW + n)*KEEP + k
  const int b = gid / (NWc * KEEPc);
  const int m = gid - b * (NWc * KEEPc);
  const int n = m / KEEPc;
  const int mt = meta[gid];
  const int w = mt & 15;
  const bool mg = (mt & 16) != 0;
  const float4* s1 =
      reinterpret_cast<const float4*>(src + (size_t)(b * Sc + n * Wc + w) * Sc);
  const float4* s2 = s1 + (mg ? (Sc / 4) : 0);
  float4* o = reinterpret_cast<float4*>(outs + (size_t)gid * Sc);
  const int t = threadIdx.x;
  if (mg) {
#pragma unroll
    for (int i = 0; i < 4; ++i) {
      const int idx = t + 256 * i;
      float4 a = s1[idx];
      const float4 c = s2[idx];
      a.x += c.x; a.y += c.y; a.z += c.z; a.w += c.w;
      o[idx] = a;
    }
  } else {
#pragma unroll
    for (int i = 0; i < 4; ++i) {
      const int idx = t + 256 * i;
      o[idx] = s1[idx];
    }
  }
}

extern "C" void kernel_launch(void* const* d_in, const int* in_sizes, int n_in,
                              void* d_out, int out_size, void* d_ws, size_t ws_size,
                              hipStream_t stream) {
  const float* x = (const float*)d_in[0];
  const float* src = (const float*)d_in[1];
  const int* pos = (const int*)d_in[2];
  const float* Wg = (const float*)d_in[3];
  float* out = (float*)d_out;
  int* meta = (int*)d_ws;

  tm_select_x<<<dim3(Bc * NWc), dim3(256), 0, stream>>>(x, pos, Wg, out, meta);
  tm_merge_s<<<dim3(Bc * NWc * KEEPc), dim3(256), 0, stream>>>(src, meta, out + X_ELEMS);
}

// Round 3
// 194.469 us; speedup vs baseline: 1.0898x; 1.0898x over previous
//
#include <hip/hip_runtime.h>
#include <math.h>

namespace {
constexpr int Bc = 4, Sc = 4096, Dc = 768, Gc = 64, Wc = 16, Rc = 4;
constexpr int NWc = Sc / Wc;          // 256 windows per batch row
constexpr int KEEPc = Wc - Rc;        // 12 kept tokens per window
constexpr int Ec = Wc - 1;            // 15 adjacent edges
constexpr int NQc = Dc / 4;           // 192 float4 per x row
constexpr size_t X_ELEMS = (size_t)Bc * NWc * KEEPc * Dc;  // 9437184
constexpr size_t S_ELEMS = (size_t)Bc * NWc * KEEPc * Sc;  // 50331648
constexpr int NROWS = Bc * NWc * KEEPc;                    // 12288 output rows

typedef float vf4 __attribute__((ext_vector_type(4)));     // native vec for nontemporal
}

// ---------------- K1: selection only (GEMM g=xw@Wg, sims, greedy match) -----
// One block per window; 4 waves split K=768; lane = G-column.
// Writes: p_out, meta[row] = w | mg<<4, wts[row] = {aS, bS}.
__global__ __launch_bounds__(256, 4)
void tm_select(const float* __restrict__ x, const int* __restrict__ pos,
               const float* __restrict__ Wg, float* __restrict__ out,
               int* __restrict__ meta, float2* __restrict__ wts) {
  const int wid = blockIdx.x;          // 0..1023
  const int b = wid >> 8;
  const int n = wid & (NWc - 1);
  const int tid = threadIdx.x;
  const int lane = tid & 63;
  const int wq = tid >> 6;

  const float4* xr4 = reinterpret_cast<const float4*>(x + (size_t)(b * Sc + n * Wc) * Dc);

  float acc[Wc];
#pragma unroll
  for (int w = 0; w < Wc; ++w) acc[w] = 0.f;

  const int q0 = wq * (NQc / 4);       // 48 float4-steps per wave
  for (int q = 0; q < NQc / 4; ++q) {
    const int d4 = q0 + q;
    const int d = d4 * 4;
    const float w0 = Wg[(size_t)d * Gc + lane];
    const float w1 = Wg[(size_t)(d + 1) * Gc + lane];
    const float w2 = Wg[(size_t)(d + 2) * Gc + lane];
    const float w3 = Wg[(size_t)(d + 3) * Gc + lane];
#pragma unroll
    for (int w = 0; w < Wc; ++w) {
      const float4 xv = xr4[w * NQc + d4];               // wave-broadcast 16B
      acc[w] = fmaf(xv.x, w0, acc[w]);
      acc[w] = fmaf(xv.y, w1, acc[w]);
      acc[w] = fmaf(xv.z, w2, acc[w]);
      acc[w] = fmaf(xv.w, w3, acc[w]);
    }
  }

  __shared__ float part[4][Wc][64];    // 16 KiB
#pragma unroll
  for (int w = 0; w < Wc; ++w) part[wq][w][lane] = acc[w];
  __syncthreads();

  float red[Wc + Ec];
  {
    float g[Wc];
#pragma unroll
    for (int w = 0; w < Wc; ++w)
      g[w] = part[0][w][lane] + part[1][w][lane] + part[2][w][lane] + part[3][w][lane];
#pragma unroll
    for (int w = 0; w < Wc; ++w) red[w] = g[w] * g[w];
#pragma unroll
    for (int e = 0; e < Ec; ++e) red[Wc + e] = g[e] * g[e + 1];
  }
#pragma unroll
  for (int m = 1; m < 64; m <<= 1) {
#pragma unroll
    for (int i = 0; i < Wc + Ec; ++i) red[i] += __shfl_xor(red[i], m, 64);
  }

  float nr[Wc];
#pragma unroll
  for (int w = 0; w < Wc; ++w) nr[w] = sqrtf(red[w]);

  float sv[Ec];
#pragma unroll
  for (int e = 0; e < Ec; ++e)
    sv[e] = red[Wc + e] / (fmaxf(nr[e], 1e-12f) * fmaxf(nr[e + 1], 1e-12f));

  // greedy: 4 rounds of max-compatible-edge (== stable sorted-scan greedy)
  unsigned sel = 0, used = 0;
#pragma unroll
  for (int round = 0; round < Rc; ++round) {
    float best = -1e30f;
    int bi = 0;
#pragma unroll
    for (int e = 0; e < Ec; ++e) {
      const bool ok = ((used >> e) & 3u) == 0u;
      const float v = ok ? sv[e] : -1e30f;
      if (v > best) { best = v; bi = e; }   // strict > => smallest index wins ties
    }
    sel |= (1u << bi);
    used |= (3u << bi);
  }

  if (wq == 0 && lane < KEEPc) {
    const int k = lane;
    int w = 0, c = 0;
#pragma unroll
    for (int t = 0; t < Wc; ++t) {
      const bool kept = (t == 0) || (((sel >> (t - 1)) & 1u) == 0u);
      if (kept && c == k) w = t;
      c += kept ? 1 : 0;
    }
    const bool mg = (w < Ec) && (((sel >> w) & 1u) != 0u);
    float wi = 0.f, wj = 0.f;
#pragma unroll
    for (int t = 0; t < Wc; ++t) {
      wi = (t == w) ? nr[t] : wi;
      wj = (t == (w + 1) && w + 1 < Wc) ? nr[t] : wj;
    }
    float aS = 1.f, bS = 0.f;
    if (mg) {
      const float tot = wi + wj + 1e-8f;
      aS = wi / tot;
      bS = wj / tot;
    }
    const int row = wid * KEEPc + k;
    meta[row] = w | (mg ? 16 : 0);
    wts[row] = make_float2(aS, bS);
    const int p = pos[b * Sc + n * Wc + w];
    out[X_ELEMS + S_ELEMS + (size_t)row] = (float)p;
  }
}

// ---------------- K2: emit one output row (x: 3 KB, s: 16 KB) per block -----
__global__ __launch_bounds__(256)
void tm_emit(const float* __restrict__ x, const float* __restrict__ src,
             const int* __restrict__ meta, const float2* __restrict__ wts,
             float* __restrict__ out) {
  const int gid = blockIdx.x;              // 0..12287 == (b*NW + n)*KEEP + k
  const int b = gid / (NWc * KEEPc);
  const int m = gid - b * (NWc * KEEPc);
  const int n = m / KEEPc;
  const int t = threadIdx.x;

  const int mt = meta[gid];
  const int w = mt & 15;
  const bool mg = (mt & 16) != 0;
  const float2 ab = wts[gid];
  const size_t tokBase = (size_t)(b * Sc + n * Wc + w);

  // ---- x row: 192 float4; threads 0..191 (wave 3 skips straight to s) ----
  if (t < NQc) {
    const vf4* xs = reinterpret_cast<const vf4*>(x + tokBase * Dc);
    const vf4 a = xs[t];
    const vf4 c = xs[t + (mg ? NQc : 0)];
    const vf4 rr = ab.x * a + ab.y * c;
    vf4* xo = reinterpret_cast<vf4*>(out + (size_t)gid * Dc);
    __builtin_nontemporal_store(rr, xo + t);
  }

  // ---- s row: 1024 float4, 4 per thread, nontemporal stream ----
  const vf4* s1 = reinterpret_cast<const vf4*>(src + tokBase * Sc);
  vf4* so = reinterpret_cast<vf4*>(out + X_ELEMS + (size_t)gid * Sc);
  if (mg) {
    const vf4* s2 = s1 + (Sc / 4);
#pragma unroll
    for (int i = 0; i < 4; ++i) {
      const int idx = t + 256 * i;
      const vf4 a = __builtin_nontemporal_load(s1 + idx);
      const vf4 c = __builtin_nontemporal_load(s2 + idx);
      __builtin_nontemporal_store(a + c, so + idx);
    }
  } else {
#pragma unroll
    for (int i = 0; i < 4; ++i) {
      const int idx = t + 256 * i;
      const vf4 a = __builtin_nontemporal_load(s1 + idx);
      __builtin_nontemporal_store(a, so + idx);
    }
  }
}

extern "C" void kernel_launch(void* const* d_in, const int* in_sizes, int n_in,
                              void* d_out, int out_size, void* d_ws, size_t ws_size,
                              hipStream_t stream) {
  const float* x = (const float*)d_in[0];
  const float* src = (const float*)d_in[1];
  const int* pos = (const int*)d_in[2];
  const float* Wg = (const float*)d_in[3];
  float* out = (float*)d_out;
  int* meta = (int*)d_ws;
  float2* wts = (float2*)((char*)d_ws + 64 * 1024);

  tm_select<<<dim3(Bc * NWc), dim3(256), 0, stream>>>(x, pos, Wg, out, meta, wts);
  tm_emit<<<dim3(NROWS), dim3(256), 0, stream>>>(x, src, meta, wts, out);
}

// Round 4
// 183.900 us; speedup vs baseline: 1.1525x; 1.0575x over previous
//
#include <hip/hip_runtime.h>
#include <math.h>

namespace {
constexpr int Bc = 4, Sc = 4096, Dc = 768, Gc = 64, Wc = 16, Rc = 4;
constexpr int NWc = Sc / Wc;          // 256 windows per batch row
constexpr int KEEPc = Wc - Rc;        // 12 kept tokens per window
constexpr int Ec = Wc - 1;            // 15 adjacent edges
constexpr int NQc = Dc / 4;           // 192 float4 per x row
constexpr size_t X_ELEMS = (size_t)Bc * NWc * KEEPc * Dc;
constexpr size_t S_ELEMS = (size_t)Bc * NWc * KEEPc * Sc;

typedef float vf4 __attribute__((ext_vector_type(4)));
}

// One block per window (1024 blocks x 512 threads, 2 blocks/CU).
// Phase 1: waves 0-3 compute g = xw@Wg partials into LDS.
// All waves: redundant butterfly reduce + greedy selection (registers only).
// Phase 2: waves 0-7 stream s-rows (8-deep NT bursts); waves 4-7 emit x-rows + p_out.
__global__ __launch_bounds__(512, 4)
void tm_fused(const float* __restrict__ x, const float* __restrict__ src,
              const int* __restrict__ pos, const float* __restrict__ Wg,
              float* __restrict__ out) {
  const int wid = blockIdx.x;          // 0..1023
  const int b = wid >> 8;
  const int n = wid & (NWc - 1);
  const int tid = threadIdx.x;
  const int lane = tid & 63;
  const int wv = tid >> 6;             // 0..7

  __shared__ float part[4][Wc][64];    // 16 KiB

  const size_t winTok = (size_t)(b * Sc + n * Wc);   // first token of window
  const float4* xr4 = reinterpret_cast<const float4*>(x + winTok * Dc);

  if (wv < 4) {
    float acc[Wc];
#pragma unroll
    for (int w = 0; w < Wc; ++w) acc[w] = 0.f;
    const int q0 = wv * (NQc / 4);     // 48 float4-steps per wave
    for (int q = 0; q < NQc / 4; ++q) {
      const int d4 = q0 + q;
      const int d = d4 * 4;
      const float w0 = Wg[(size_t)d * Gc + lane];
      const float w1 = Wg[(size_t)(d + 1) * Gc + lane];
      const float w2 = Wg[(size_t)(d + 2) * Gc + lane];
      const float w3 = Wg[(size_t)(d + 3) * Gc + lane];
#pragma unroll
      for (int w = 0; w < Wc; ++w) {
        const float4 xv = xr4[w * NQc + d4];           // wave-broadcast 16B
        acc[w] = fmaf(xv.x, w0, acc[w]);
        acc[w] = fmaf(xv.y, w1, acc[w]);
        acc[w] = fmaf(xv.z, w2, acc[w]);
        acc[w] = fmaf(xv.w, w3, acc[w]);
      }
    }
#pragma unroll
    for (int w = 0; w < Wc; ++w) part[wv][w][lane] = acc[w];
  }
  __syncthreads();

  // ---- redundant reduce + selection in every wave (all lanes end equal) ----
  float red[Wc + Ec];
  {
    float g[Wc];
#pragma unroll
    for (int w = 0; w < Wc; ++w)
      g[w] = part[0][w][lane] + part[1][w][lane] + part[2][w][lane] + part[3][w][lane];
#pragma unroll
    for (int w = 0; w < Wc; ++w) red[w] = g[w] * g[w];
#pragma unroll
    for (int e = 0; e < Ec; ++e) red[Wc + e] = g[e] * g[e + 1];
  }
#pragma unroll
  for (int m = 1; m < 64; m <<= 1) {
#pragma unroll
    for (int i = 0; i < Wc + Ec; ++i) red[i] += __shfl_xor(red[i], m, 64);
  }

  float nr[Wc];
#pragma unroll
  for (int w = 0; w < Wc; ++w) nr[w] = sqrtf(red[w]);

  float sv[Ec];
#pragma unroll
  for (int e = 0; e < Ec; ++e)
    sv[e] = red[Wc + e] / (fmaxf(nr[e], 1e-12f) * fmaxf(nr[e + 1], 1e-12f));

  unsigned sel = 0, used = 0;
#pragma unroll
  for (int r = 0; r < Rc; ++r) {
    float best = -1e30f;
    int bi = 0;
#pragma unroll
    for (int e = 0; e < Ec; ++e) {
      const bool ok = ((used >> e) & 3u) == 0u;
      const float v = ok ? sv[e] : -1e30f;
      if (v > best) { best = v; bi = e; }   // strict > => smallest index wins ties
    }
    sel |= (1u << bi);
    used |= (3u << bi);
  }

  // kept-row map: k-th kept token -> window-local token w, merged flag
  auto rowmap = [&](int k, int& w_out, bool& mg_out) {
    int ww = 0, c = 0;
#pragma unroll
    for (int t2 = 0; t2 < Wc; ++t2) {
      const bool kept = (t2 == 0) || (((sel >> (t2 - 1)) & 1u) == 0u);
      if (kept && c == k) ww = t2;
      c += kept ? 1 : 0;
    }
    w_out = ww;
    mg_out = (ww < Ec) && (((sel >> ww) & 1u) != 0u);
  };

  // ---- phase 2a: s rows. wave wv handles k = wv, wv+8 (waves 0-3 get 2) ----
  float* souts = out + X_ELEMS;
  for (int k = wv; k < KEEPc; k += 8) {
    int w; bool mg; rowmap(k, w, mg);
    const vf4* p1 = reinterpret_cast<const vf4*>(src + (winTok + w) * Sc);
    vf4* o = reinterpret_cast<vf4*>(souts + ((size_t)wid * KEEPc + k) * Sc);
    if (mg) {
      const vf4* p2 = p1 + (Sc / 4);
#pragma unroll
      for (int c2 = 0; c2 < 2; ++c2) {
        vf4 v[8], u[8];
#pragma unroll
        for (int j = 0; j < 8; ++j)
          v[j] = __builtin_nontemporal_load(p1 + lane + 64 * (8 * c2 + j));
#pragma unroll
        for (int j = 0; j < 8; ++j)
          u[j] = __builtin_nontemporal_load(p2 + lane + 64 * (8 * c2 + j));
#pragma unroll
        for (int j = 0; j < 8; ++j)
          __builtin_nontemporal_store(v[j] + u[j], o + lane + 64 * (8 * c2 + j));
      }
    } else {
#pragma unroll
      for (int c2 = 0; c2 < 2; ++c2) {
        vf4 v[8];
#pragma unroll
        for (int j = 0; j < 8; ++j)
          v[j] = __builtin_nontemporal_load(p1 + lane + 64 * (8 * c2 + j));
#pragma unroll
        for (int j = 0; j < 8; ++j)
          __builtin_nontemporal_store(v[j], o + lane + 64 * (8 * c2 + j));
      }
    }
  }

  // ---- phase 2b: x rows (waves 4-7, 3 rows each) + p_out (wave 7) ----
  if (wv >= 4) {
#pragma unroll
    for (int j3 = 0; j3 < 3; ++j3) {
      const int k = (wv - 4) + 4 * j3;
      int w; bool mg; rowmap(k, w, mg);
      float aS = 1.f, bS = 0.f;
      if (mg) {
        float wi_ = 0.f, wj_ = 0.f;
#pragma unroll
        for (int t2 = 0; t2 < Wc; ++t2) {
          wi_ = (t2 == w) ? nr[t2] : wi_;
          wj_ = (t2 == w + 1) ? nr[t2] : wj_;
        }
        const float tot = wi_ + wj_ + 1e-8f;
        aS = wi_ / tot;
        bS = wj_ / tot;
      }
      const vf4* xs = reinterpret_cast<const vf4*>(x + (winTok + w) * Dc);
      vf4* xo = reinterpret_cast<vf4*>(out + ((size_t)wid * KEEPc + k) * Dc);
#pragma unroll
      for (int j = 0; j < 3; ++j) {
        const int idx = lane + 64 * j;
        const vf4 a = xs[idx];
        const vf4 c = xs[idx + (mg ? NQc : 0)];
        __builtin_nontemporal_store(aS * a + bS * c, xo + idx);
      }
    }
    if (wv == 7 && lane < KEEPc) {
      int w; bool mg; rowmap(lane, w, mg);
      out[X_ELEMS + S_ELEMS + (size_t)wid * KEEPc + lane] =
          (float)pos[winTok + w];
    }
  }
}

extern "C" void kernel_launch(void* const* d_in, const int* in_sizes, int n_in,
                              void* d_out, int out_size, void* d_ws, size_t ws_size,
                              hipStream_t stream) {
  const float* x = (const float*)d_in[0];
  const float* src = (const float*)d_in[1];
  const int* pos = (const int*)d_in[2];
  const float* Wg = (const float*)d_in[3];
  float* out = (float*)d_out;

  tm_fused<<<dim3(Bc * NWc), dim3(512), 0, stream>>>(x, src, pos, Wg, out);
}